// Round 7
// baseline (653.375 us; speedup 1.0000x reference)
//
#include <hip/hip_runtime.h>
#include <math.h>

// Problem constants (reference: x[8,2048,1024] f32, W[1024,64] f32)
#define BB 8
#define NN 2048
#define DD 1024
#define EE 64
#define CAP 64
#define NTOK (BB * NN)          // 16384
#define OUT_T_FLOATS 67108864   // 8*2048*64*64 per tensor

// Session ledger (measured):
//   dur = ~340us harness poison-drain + work
//   G(v4) = 58us [rep-x3 r4] | S = 11us [rep-x3 r5] | dense F v1 = ~200us
//   r6: memset(512MiB)+sparse = ~142us -> dur 551.
//   r7 (this): fuse the 512MiB zeroing INTO G's FMA loop (write BW overlaps
//   VALU-bound compute; G's mem pipes were ~idle: 67MB reads only).
//   Fused-G floor = max(58 compute, 604MB @ 6.3TB/s = 96) ~= 100-125us.

// Workspace layout (bytes):
//   recs      float4[NTOK]   @ 0        {g1n, g2n, bits(i1), bits(i2 | flag<<8)}
//   frecs     float4[NTOK]   @ 262144   {g1|0, g2|0, bits(e1*64+p1 | -1), bits(e2*64+p2 | -1)}
//   dens      float[256*64]  @ 524288   per-gating-block density partials
//   lossp     float[8]       @ 589824   per-batch loss partials

// ---------------------------------------------------------------------------
// Kernel G (v6 = v4 + fused output zeroing): 256 blocks x 1024 threads.
// Compute mapping verbatim from the measured-58us v4. Additionally each
// block zeroes its 2 MiB slice of out (256 x 2MiB = 512MiB = both tensors):
// 2 float4 stores per c-iteration per thread (64 iters x 2 x 1024 thr x 16B
// = 2MiB), wave-contiguous 1KB segments. Stores are independent of all
// compute; they stream on the otherwise-idle write path.
// ---------------------------------------------------------------------------
__global__ __launch_bounds__(1024, 4) void gating_kernel(
    const float* __restrict__ x, const float* __restrict__ W,
    float4* __restrict__ recs, float* __restrict__ dens,
    float4* __restrict__ outz)
{
    __shared__ float red[4][64][65];    // [kslice][expert][token+pad] 65 KB
    __shared__ float dred[4][64];

    const int tid  = threadIdx.x;
    const int lane = tid & 63;                                   // token-in-block
    const int wave = __builtin_amdgcn_readfirstlane(tid >> 6);
    const int ks   = wave & 3;                                   // k-slice (256 k)
    const int eq   = wave >> 2;                                  // expert quarter
    const int tok  = blockIdx.x * 64 + lane;

    float acc[16];
#pragma unroll
    for (int j = 0; j < 16; ++j) acc[j] = 0.f;

    const float4* xq = (const float4*)(x + (size_t)tok * DD + ks * 256);
    const float*  wq = W + (size_t)(ks * 256) * EE + eq * 16;    // wave-uniform

    // this block's zero-slice: 131072 float4 = 2 MiB
    float4* zb = outz + (size_t)blockIdx.x * 131072 + tid;
    const float4 zv = make_float4(0.f, 0.f, 0.f, 0.f);

#pragma unroll 2
    for (int c = 0; c < 64; ++c) {           // 64 float4 of x = 256 k
        const float4 xv = xq[c];

        // fused zeroing: 2 KiB-per-wave streaming stores on the idle write path
        zb[(size_t)(2 * c) * 1024]     = zv;
        zb[(size_t)(2 * c + 1) * 1024] = zv;

        const float xs[4] = {xv.x, xv.y, xv.z, xv.w};
#pragma unroll
        for (int kk = 0; kk < 4; ++kk) {
            const float4* wr = (const float4*)(wq + (size_t)(c * 4 + kk) * EE);
            const float4 w0 = wr[0], w1 = wr[1], w2 = wr[2], w3 = wr[3];
            acc[ 0] = fmaf(xs[kk], w0.x, acc[ 0]);
            acc[ 1] = fmaf(xs[kk], w0.y, acc[ 1]);
            acc[ 2] = fmaf(xs[kk], w0.z, acc[ 2]);
            acc[ 3] = fmaf(xs[kk], w0.w, acc[ 3]);
            acc[ 4] = fmaf(xs[kk], w1.x, acc[ 4]);
            acc[ 5] = fmaf(xs[kk], w1.y, acc[ 5]);
            acc[ 6] = fmaf(xs[kk], w1.z, acc[ 6]);
            acc[ 7] = fmaf(xs[kk], w1.w, acc[ 7]);
            acc[ 8] = fmaf(xs[kk], w2.x, acc[ 8]);
            acc[ 9] = fmaf(xs[kk], w2.y, acc[ 9]);
            acc[10] = fmaf(xs[kk], w2.z, acc[10]);
            acc[11] = fmaf(xs[kk], w2.w, acc[11]);
            acc[12] = fmaf(xs[kk], w3.x, acc[12]);
            acc[13] = fmaf(xs[kk], w3.y, acc[13]);
            acc[14] = fmaf(xs[kk], w3.z, acc[14]);
            acc[15] = fmaf(xs[kk], w3.w, acc[15]);
        }
    }

    // ---- one-shot cross-slice reduce via LDS
#pragma unroll
    for (int j = 0; j < 16; ++j)
        red[ks][eq * 16 + j][lane] = acc[j];     // lane stride 1: conflict-free
    __syncthreads();

    // ---- epilogue: waves 0-3, wave w handles tokens [16w,16w+16); lane = expert
    if (wave < 4) {
        const int t0 = wave * 16;
        float densacc = 0.f;
#pragma unroll 1
        for (int ti = 0; ti < 16; ++ti) {
            const int t = t0 + ti;
            const float lv = ((red[0][lane][t] + red[1][lane][t])
                            + red[2][lane][t]) + red[3][lane][t];  // stride 65: free

            // argmax: value desc, index asc on ties (matches jnp.argmax)
            float v = lv; int bi = lane;
#pragma unroll
            for (int off = 32; off; off >>= 1) {
                float ov = __shfl_xor(v, off);
                int   oi = __shfl_xor(bi, off);
                if (ov > v || (ov == v && oi < bi)) { v = ov; bi = oi; }
            }
            const float m1 = v; const int i1 = bi;
            float v2 = (lane == i1) ? -INFINITY : lv; int b2 = lane;
#pragma unroll
            for (int off = 32; off; off >>= 1) {
                float ov = __shfl_xor(v2, off);
                int   oi = __shfl_xor(b2, off);
                if (ov > v2 || (ov == v2 && oi < b2)) { v2 = ov; b2 = oi; }
            }
            const float m2 = v2; const int i2 = b2;

            float ex = expf(lv - m1);
            float Z = ex;
#pragma unroll
            for (int off = 32; off; off >>= 1) Z += __shfl_xor(Z, off);
            float g1 = 1.0f / Z;               // p[i1]
            float g2 = expf(m2 - m1) * g1;     // p[i2]
            float den = g1 + g2 + 1e-9f;
            float g1n = g1 / den;
            float g2n = g2 / den;
            int flag = (g2n > 0.2f) ? 1 : 0;   // threshold on NORMALIZED gate_2

            densacc += ex * g1;                // p_t[lane] for density proxy

            if (lane == 0)
                recs[blockIdx.x * 64 + t] =
                    make_float4(g1n, g2n, __int_as_float(i1),
                                __int_as_float(i2 | (flag << 8)));
        }
        dred[wave][lane] = densacc;
    }
    __syncthreads();
    if (tid < 64) {
        float s = dred[0][tid] + dred[1][tid] + dred[2][tid] + dred[3][tid];
        dens[blockIdx.x * 64 + tid] = s;       // per-block partial, no atomics
    }
}

// ---------------------------------------------------------------------------
// Kernel S (609-baseline verbatim): ballot-based parallel rank for
// position-in-expert. 1 block/batch, 1024 threads. Measured: 11us.
// ---------------------------------------------------------------------------
__global__ __launch_bounds__(1024) void scan_kernel(
    const float4* __restrict__ recs, const float* __restrict__ dens,
    float4* __restrict__ frecs, float* __restrict__ lossp)
{
    const int b = blockIdx.x;
    __shared__ int hist1[32][64], pre1[32][64];
    __shared__ int hist2[32][64], pre2[32][64];
    __shared__ int base2[64];
    __shared__ float dsum[64];

    const int tid = threadIdx.x;
    const int lane = tid & 63;
    const int wave = tid >> 6;

    float4 r[2];
    int e1[2], e2[2], fl[2], rank1[2], rank2[2];
    const unsigned long long below = (1ull << lane) - 1ull;

#pragma unroll
    for (int u = 0; u < 2; ++u) {
        const int g = 2 * wave + u;
        const int tok = g * 64 + lane;
        float4 rr = recs[b * NN + tok];
        r[u] = rr;
        e1[u] = __float_as_int(rr.z);
        int i2f = __float_as_int(rr.w);
        e2[u] = i2f & 63;
        fl[u] = i2f >> 8;

        unsigned long long m = ~0ull, mv = ~0ull;
#pragma unroll
        for (int bit = 0; bit < 6; ++bit) {
            unsigned long long vt = __ballot((e1[u] >> bit) & 1);
            m  &= ((e1[u] >> bit) & 1) ? vt : ~vt;
            mv &= ((lane  >> bit) & 1) ? vt : ~vt;
        }
        rank1[u] = __popcll(m & below);
        hist1[g][lane] = __popcll(mv);

        unsigned long long fv = __ballot(fl[u]);
        m = fv; mv = fv;
#pragma unroll
        for (int bit = 0; bit < 6; ++bit) {
            unsigned long long vt = __ballot((e2[u] >> bit) & 1);
            m  &= ((e2[u] >> bit) & 1) ? vt : ~vt;
            mv &= ((lane  >> bit) & 1) ? vt : ~vt;
        }
        rank2[u] = __popcll(m & below);
        hist2[g][lane] = __popcll(mv);
    }

    if (wave == 0) {  // density sums: 32 gating blocks per batch
        float s = 0.f;
        for (int k = 0; k < 32; ++k) s += dens[(b * 32 + k) * 64 + lane];
        dsum[lane] = s;
    }
    __syncthreads();

    if (wave == 0) {  // cross-group exclusive prefix, lane = expert
        int run = 0;
#pragma unroll
        for (int g = 0; g < 32; ++g) { pre1[g][lane] = run; run += hist1[g][lane]; }
        base2[lane] = run < CAP ? run : CAP;     // mask_1_count = min(count, cap)
        int run2 = 0;
#pragma unroll
        for (int g = 0; g < 32; ++g) { pre2[g][lane] = run2; run2 += hist2[g][lane]; }
        float v = dsum[lane] * (float)run;       // UNCAPPED count for loss
#pragma unroll
        for (int off = 32; off; off >>= 1) v += __shfl_xor(v, off);
        if (lane == 0) lossp[b] = v;
    }
    __syncthreads();

#pragma unroll
    for (int u = 0; u < 2; ++u) {
        const int g = 2 * wave + u;
        const int tok = g * 64 + lane;
        int p1 = rank1[u] + pre1[g][e1[u]];
        int k1 = p1 < CAP;
        int p2 = rank2[u] + pre2[g][e2[u]] + base2[e2[u]];
        int k2 = fl[u] && (p2 < CAP);
        float4 fr;
        fr.x = k1 ? r[u].x : 0.f;
        fr.y = k2 ? r[u].y : 0.f;
        fr.z = __int_as_float(k1 ? (e1[u] * CAP + p1) : -1);
        fr.w = __int_as_float(k2 ? (e2[u] * CAP + p2) : -1);
        frecs[b * NN + tok] = fr;
    }
}

// ---------------------------------------------------------------------------
// Kernel F (sparse, r6 verbatim): out already zeroed (by fused G). Scatter
// the <=2 nonzero (expert,pos) slots per token per tensor + loss scalar.
// ---------------------------------------------------------------------------
__global__ __launch_bounds__(256) void sparse_fill_kernel(
    const float4* __restrict__ frecs, const float* __restrict__ lossp,
    float* __restrict__ out)
{
    const int token = blockIdx.x * 256 + threadIdx.x;   // 0 .. 16383
    const float4 r = frecs[token];
    float* __restrict__ dsp = out;
    float* __restrict__ cmb = out + (size_t)OUT_T_FLOATS;
    const size_t base = (size_t)token * (EE * CAP);

    const int p1 = __float_as_int(r.z);
    if (p1 >= 0) {
        dsp[base + p1] = 1.0f;
        cmb[base + p1] = r.x;
    }
    const int p2 = __float_as_int(r.w);
    if (p2 >= 0) {
        dsp[base + p2] = 1.0f;
        cmb[base + p2] = r.y;
    }

    if (token == 0) {
        float s = 0.f;
        for (int k = 0; k < 8; ++k) s += lossp[k];
        // loss = sum_b lossp[b] * e^2 / (b*e*n^2) = s / 524288
        out[2 * (size_t)OUT_T_FLOATS] = s * (1.0f / 524288.0f);
    }
}

extern "C" void kernel_launch(void* const* d_in, const int* in_sizes, int n_in,
                              void* d_out, int out_size, void* d_ws, size_t ws_size,
                              hipStream_t stream)
{
    const float* x = (const float*)d_in[0];
    const float* W = (const float*)d_in[1];
    float* out = (float*)d_out;
    char* ws = (char*)d_ws;

    float4* recs  = (float4*)(ws);
    float4* frecs = (float4*)(ws + 262144);
    float*  dens  = (float*)(ws + 524288);
    float*  lossp = (float*)(ws + 589824);

    gating_kernel<<<256, 1024, 0, stream>>>(x, W, recs, dens, (float4*)out);
    scan_kernel<<<8, 1024, 0, stream>>>(recs, dens, frecs, lossp);
    sparse_fill_kernel<<<NTOK / 256, 256, 0, stream>>>(frecs, lossp, out);
}